// Round 1
// 177.156 us; speedup vs baseline: 1.1103x; 1.1103x over previous
//
#include <hip/hip_runtime.h>
#include <math.h>

#define BATCH 128
#define NN 512
#define PARTS 8
#define INF_F 1000000000.0f
#define MU_F 1e-8f
#define SAFE_T 0.05f
// float(2*pi) and float(2*pi/8) — match reference f32 constants
#define TWO_PI_F 6.28318530717958647692f
#define STEP_F 0.78539816339744830962f
#define NT 1024   // 16 waves/block, 1 block per CU

__global__ __launch_bounds__(NT) void pc_kernel(
    const float* __restrict__ seg_maps,   // (B, N, N)
    const float* __restrict__ paras,      // (B, 4): Wx, Wy, bx, by
    const float* __restrict__ traj,       // (B, 8, 2)
    const float* __restrict__ cpos,       // (B, 1, 2)
    float* __restrict__ out)              // (B, 16, 3)
{
    const int b   = blockIdx.x;
    const int tid = threadIdx.x;

    const float Wx = paras[b * 4 + 0];
    const float Wy = paras[b * 4 + 1];
    const float bx = paras[b * 4 + 2];
    const float by = paras[b * 4 + 3];
    const float cx = cpos[b * 2 + 0];
    const float cy = cpos[b * 2 + 1];

    // moving_vector = (traj[7]+c) - (traj[0]+c)  — keep the reference's op order
    const float o0x = traj[b * 16 + 0]  + cx;
    const float o0y = traj[b * 16 + 1]  + cy;
    const float o7x = traj[b * 16 + 14] + cx;
    const float o7y = traj[b * 16 + 15] + cy;
    const float mvx = o7x - o0x;
    const float mvy = o7y - o0y;
    const float ml  = __fsqrt_rn(__fadd_rn(__fmul_rn(mvx, mvx), __fmul_rn(mvy, mvy)));
    const float r   = 2.0f * ml;   // VISION_RADIUS = 2.0

    // Pixel-space bounding box of the valid disk: |((i-bx)/Wx) - cx| <= r
    // => i in [bx + Wx*(cx-r), bx + Wx*(cx+r)]  (Wx > 0). Margin +-2 px for fp slop.
    int ilo = (int)floorf(bx + Wx * (cx - r)) - 2;
    int ihi = (int)ceilf (bx + Wx * (cx + r)) + 2;
    int jlo = (int)floorf(by + Wy * (cy - r)) - 2;
    int jhi = (int)ceilf (by + Wy * (cy + r)) + 2;
    ilo = max(ilo, 0); ihi = min(ihi, NN - 1);
    jlo = max(jlo, 0); jhi = min(jhi, NN - 1);

    int h = 0, w = 0;
    if (ilo <= ihi && jlo <= jhi) {
        h = ihi - ilo + 1;
        w = jhi - jlo + 1;
    }

    // Precompute dx per row and dy per column ONCE (bit-identical ops to the
    // reference: __fdiv_rn((float)i - bx, Wx) - cx per unique coordinate).
    // Removes 2 fdiv per pixel and all runtime int div/mod from the hot loop.
    __shared__ float dxs[NN];
    __shared__ float dys[NN];
    for (int t = tid; t < h; t += NT)
        dxs[t] = __fdiv_rn((float)(ilo + t) - bx, Wx) - cx;
    for (int t = tid; t < w; t += NT)
        dys[t] = __fdiv_rn((float)(jlo + t) - by, Wy) - cy;
    __syncthreads();

    float mind[PARTS];
#pragma unroll
    for (int k = 0; k < PARTS; ++k) mind[k] = INF_F;

    if (h > 0) {
        const float* mb = seg_maps + (size_t)b * NN * NN;
        const int ti = tid >> 6;   // wave index 0..15 → row stripe (wave-uniform)
        const int tj = tid & 63;   // lane → column (coalesced 64-wide row reads)

        for (int jj = tj; jj < w; jj += 64) {
            const float dy = dys[jj];          // stride-1 LDS: 2 lanes/bank, free
            const int j = jlo + jj;
            for (int ii = ti; ii < h; ii += 16) {
                const float dx = dxs[ii];      // wave-uniform → LDS broadcast
                const float m  = mb[(ilo + ii) * NN + j];
                const float s  = __fadd_rn(__fmul_rn(dx, dx), __fmul_rn(dy, dy));
                const float dist = __fsqrt_rn(s);
                // valid = ~(m <= 0.05) & (dist <= r)
                if (m > SAFE_T && dist <= r) {
                    const float ang = atan2f(dx, dy);
                    const float am  = (ang < 0.0f) ? (ang + (float)TWO_PI_F) : ang;
                    const int bin   = (int)__fdiv_rn(am, (float)STEP_F);  // trunc == astype(int32)
                    if (bin < PARTS) {  // reference's segment_min drops bin==8 (am rounded to 2π)
                        const float ed = __fdiv_rn(dist + MU_F, m + MU_F);
                        mind[bin] = fminf(mind[bin], ed);
                    }
                }
            }
        }
    }

    // Reduce: shuffle within each 64-lane wave, then LDS across the 16 waves.
    __shared__ float red[16 * PARTS];
    const int lane = tid & 63;
    const int wave = tid >> 6;
#pragma unroll
    for (int k = 0; k < PARTS; ++k) {
        float v = mind[k];
#pragma unroll
        for (int off = 32; off >= 1; off >>= 1)
            v = fminf(v, __shfl_xor(v, off, 64));
        if (lane == 0) red[wave * PARTS + k] = v;
    }
    __syncthreads();

    // (16, 3) output per batch; rows 8..15 are the zero pad.
    if (tid < 48) {
        const int k = tid / 3;
        const int c = tid % 3;
        float val = 0.0f;
        if (k < PARTS) {
            float mn = INF_F;
#pragma unroll
            for (int wv = 0; wv < 16; ++wv)
                mn = fminf(mn, red[wv * PARTS + k]);
            if (mn < INF_F) {           // obstacle
                if (c == 0)      val = ml;
                else if (c == 1) val = mn;
                else             val = __fdiv_rn(__fmul_rn((float)TWO_PI_F, (float)k + 0.5f), 8.0f);
            }
        }
        out[b * 48 + k * 3 + c] = val;
    }
}

extern "C" void kernel_launch(void* const* d_in, const int* in_sizes, int n_in,
                              void* d_out, int out_size, void* d_ws, size_t ws_size,
                              hipStream_t stream) {
    const float* seg_maps = (const float*)d_in[0];  // (128, 512, 512)
    const float* paras    = (const float*)d_in[1];  // (128, 4)
    const float* traj     = (const float*)d_in[2];  // (128, 8, 2)
    const float* cpos     = (const float*)d_in[3];  // (128, 1, 2)
    // d_in[4] = map_pos_pixel — recomputed inline, never loaded.

    pc_kernel<<<BATCH, NT, 0, stream>>>(seg_maps, paras, traj, cpos, (float*)d_out);
}

// Round 2
// 174.048 us; speedup vs baseline: 1.1302x; 1.0179x over previous
//
#include <hip/hip_runtime.h>
#include <math.h>

#define BATCH 128
#define NN 512
#define PARTS 8
#define YSPLIT 8          // blocks per batch (row interleave)
#define INF_F 1000000000.0f
#define MU_F 1e-8f
#define SAFE_T 0.05f
// float(2*pi) and float(2*pi/8) — match reference f32 constants
#define TWO_PI_F 6.28318530717958647692f
#define STEP_F 0.78539816339744830962f

// ---------------------------------------------------------------------------
// Kernel 1: per-(batch, row-stripe) partial partition minima → ws[b][y][k].
// Plain stores to private slots: no atomics, no workspace init required
// (every slot is unconditionally written each launch, so poison is harmless).
// ---------------------------------------------------------------------------
__global__ __launch_bounds__(256) void pc_compute(
    const float* __restrict__ seg_maps,   // (B, N, N)
    const float* __restrict__ paras,      // (B, 4): Wx, Wy, bx, by
    const float* __restrict__ traj,       // (B, 8, 2)
    const float* __restrict__ cpos,       // (B, 1, 2)
    float* __restrict__ ws)               // (B, YSPLIT, PARTS) partial minima
{
    const int b   = blockIdx.x;
    const int y   = blockIdx.y;           // 0..YSPLIT-1 row stripe
    const int tid = threadIdx.x;

    const float Wx = paras[b * 4 + 0];
    const float Wy = paras[b * 4 + 1];
    const float bx = paras[b * 4 + 2];
    const float by = paras[b * 4 + 3];
    const float cx = cpos[b * 2 + 0];
    const float cy = cpos[b * 2 + 1];

    // moving_vector = (traj[7]+c) - (traj[0]+c)  — keep the reference's op order
    const float o0x = traj[b * 16 + 0]  + cx;
    const float o0y = traj[b * 16 + 1]  + cy;
    const float o7x = traj[b * 16 + 14] + cx;
    const float o7y = traj[b * 16 + 15] + cy;
    const float mvx = o7x - o0x;
    const float mvy = o7y - o0y;
    const float ml  = __fsqrt_rn(__fadd_rn(__fmul_rn(mvx, mvx), __fmul_rn(mvy, mvy)));
    const float r   = 2.0f * ml;   // VISION_RADIUS = 2.0

    // Pixel-space bounding box of the valid disk: |((i-bx)/Wx) - cx| <= r
    // => i in [bx + Wx*(cx-r), bx + Wx*(cx+r)]  (Wx > 0). Margin +-2 px for fp slop.
    int ilo = (int)floorf(bx + Wx * (cx - r)) - 2;
    int ihi = (int)ceilf (bx + Wx * (cx + r)) + 2;
    int jlo = (int)floorf(by + Wy * (cy - r)) - 2;
    int jhi = (int)ceilf (by + Wy * (cy + r)) + 2;
    ilo = max(ilo, 0); ihi = min(ihi, NN - 1);
    jlo = max(jlo, 0); jhi = min(jhi, NN - 1);

    float mind[PARTS];
#pragma unroll
    for (int k = 0; k < PARTS; ++k) mind[k] = INF_F;

    if (ilo <= ihi && jlo <= jhi) {
        const int h = ihi - ilo + 1;
        const int w = jhi - jlo + 1;
        const float* mb = seg_maps + (size_t)b * NN * NN;

        const int ti = tid >> 6;          // wave 0..3
        const int tj = tid & 63;          // lane → column (coalesced)
        const int gw = y * 4 + ti;        // global row worker 0..31

        for (int jj = tj; jj < w; jj += 64) {
            // dy depends only on the column — one __fdiv_rn per column,
            // bit-identical to the reference's (pixel - b)/W - c.
            const float dy = __fdiv_rn((float)(jlo + jj) - by, Wy) - cy;
            const int j = jlo + jj;
            for (int ii = gw; ii < h; ii += 32) {
                const float dx = __fdiv_rn((float)(ilo + ii) - bx, Wx) - cx;
                const float m  = mb[(ilo + ii) * NN + j];
                const float s  = __fadd_rn(__fmul_rn(dx, dx), __fmul_rn(dy, dy));
                const float dist = __fsqrt_rn(s);
                // valid = ~(m <= 0.05) & (dist <= r)
                if (m > SAFE_T && dist <= r) {
                    const float ang = atan2f(dx, dy);
                    const float am  = (ang < 0.0f) ? (ang + (float)TWO_PI_F) : ang;
                    const int bin   = (int)__fdiv_rn(am, (float)STEP_F);  // trunc == astype(int32)
                    if (bin < PARTS) {  // reference's segment_min drops bin==8 (am rounded to 2π)
                        const float ed = __fdiv_rn(dist + MU_F, m + MU_F);
                        mind[bin] = fminf(mind[bin], ed);
                    }
                }
            }
        }
    }

    // Reduce: shuffle within each 64-lane wave, then LDS across the 4 waves.
    __shared__ float red[4 * PARTS];
    const int lane = tid & 63;
    const int wave = tid >> 6;
#pragma unroll
    for (int k = 0; k < PARTS; ++k) {
        float v = mind[k];
#pragma unroll
        for (int off = 32; off >= 1; off >>= 1)
            v = fminf(v, __shfl_xor(v, off, 64));
        if (lane == 0) red[wave * PARTS + k] = v;
    }
    __syncthreads();

    if (tid < PARTS) {
        const float mn = fminf(fminf(red[0 * PARTS + tid], red[1 * PARTS + tid]),
                               fminf(red[2 * PARTS + tid], red[3 * PARTS + tid]));
        ws[(b * YSPLIT + y) * PARTS + tid] = mn;
    }
}

// ---------------------------------------------------------------------------
// Kernel 2: reduce the YSPLIT partials per (batch, partition) and apply the
// obstacle transform. One thread per output element (128 * 48 = 6144).
// ---------------------------------------------------------------------------
__global__ __launch_bounds__(256) void pc_finalize(
    const float* __restrict__ traj,       // (B, 8, 2)
    const float* __restrict__ cpos,       // (B, 1, 2)
    const float* __restrict__ ws,         // (B, YSPLIT, PARTS)
    float* __restrict__ out)              // (B, 16, 3)
{
    const int g = blockIdx.x * 256 + threadIdx.x;   // 0 .. 6143
    if (g >= BATCH * 48) return;
    const int b   = g / 48;
    const int rem = g - b * 48;
    const int k   = rem / 3;
    const int c   = rem - k * 3;

    float val = 0.0f;
    if (k < PARTS) {
        float mn = INF_F;
#pragma unroll
        for (int y = 0; y < YSPLIT; ++y)
            mn = fminf(mn, ws[(b * YSPLIT + y) * PARTS + k]);
        if (mn < INF_F) {                 // obstacle present in this partition
            if (c == 0) {
                const float cx = cpos[b * 2 + 0];
                const float cy = cpos[b * 2 + 1];
                const float o0x = traj[b * 16 + 0]  + cx;
                const float o0y = traj[b * 16 + 1]  + cy;
                const float o7x = traj[b * 16 + 14] + cx;
                const float o7y = traj[b * 16 + 15] + cy;
                const float mvx = o7x - o0x;
                const float mvy = o7y - o0y;
                val = __fsqrt_rn(__fadd_rn(__fmul_rn(mvx, mvx), __fmul_rn(mvy, mvy)));
            } else if (c == 1) {
                val = mn;
            } else {
                val = __fdiv_rn(__fmul_rn((float)TWO_PI_F, (float)k + 0.5f), 8.0f);
            }
        }
    }
    out[g] = val;   // out[b*48 + k*3 + c] == out[g]; rows 8..15 stay zero
}

extern "C" void kernel_launch(void* const* d_in, const int* in_sizes, int n_in,
                              void* d_out, int out_size, void* d_ws, size_t ws_size,
                              hipStream_t stream) {
    const float* seg_maps = (const float*)d_in[0];  // (128, 512, 512)
    const float* paras    = (const float*)d_in[1];  // (128, 4)
    const float* traj     = (const float*)d_in[2];  // (128, 8, 2)
    const float* cpos     = (const float*)d_in[3];  // (128, 1, 2)
    // d_in[4] = map_pos_pixel — recomputed inline, never loaded.

    float* ws = (float*)d_ws;                       // 128*8*8 floats = 32 KB

    pc_compute<<<dim3(BATCH, YSPLIT), 256, 0, stream>>>(seg_maps, paras, traj, cpos, ws);
    pc_finalize<<<(BATCH * 48 + 255) / 256, 256, 0, stream>>>(traj, cpos, ws, (float*)d_out);
}